// Round 5
// baseline (65.840 us; speedup 1.0000x reference)
//
#include <hip/hip_runtime.h>

constexpr int DIN  = 256;
constexpr int DOUT = 32;
constexpr int ET   = 64;     // entities per block (k1)
constexpr int ZPT  = 100;    // float4 zero-stores per thread (k1): 512*256*100 = out_size/4

typedef float vfloat4 __attribute__((ext_vector_type(4)));

__device__ __forceinline__ void gload_lds16(const float* g, float* l) {
    __builtin_amdgcn_global_load_lds(
        (const __attribute__((address_space(1))) void*)g,
        (__attribute__((address_space(3))) void*)l, 16, 0, 0);
}

// k1: fused {zero out} + {GEMM emb*W -> relu -> ws}.
// Zero stores are nontemporal fire-and-forget; counted vmcnt keeps them in
// flight across barriers (T4) so the kernel runs at write-BW while compute
// hides underneath. Loads are global_load_lds (no reg readback -> no compiler
// vmcnt drains); LDS emb tile granule-XOR-swizzled on the SOURCE side, read
// with the same XOR (linear LDS dest, rule #21).
__global__ __launch_bounds__(256)
void k1_zero_gemm(const float* __restrict__ emb,
                  const float* __restrict__ weight,
                  const float* __restrict__ bias,
                  float* __restrict__ out,
                  float* __restrict__ ws,
                  int nent, int zTotal4)
{
    __shared__ float s_emb[2][ET * 64];   // 2 x 16 KB
    __shared__ float s_w[2][64 * DOUT];   // 2 x 8 KB

    const int tid  = threadIdx.x;
    const int lane = tid & 63;
    const int wv   = tid >> 6;     // wave 0..3
    const int og   = tid & 7;      // output group (4 cols)
    const int eg   = tid >> 3;     // 0..31; thread owns entities eg, eg+32
    const int eb   = blockIdx.x * ET;
    const int es   = eg & 7;

    // ---- issue tile-0 loads (6 gload_lds per wave)
    {
        const int r0 = wv * 16;
        #pragma unroll
        for (int j = 0; j < 4; ++j) {
            const int rb  = r0 + j * 4;
            const int row = rb + (lane >> 4);
            int e = eb + row; if (e >= nent) e = nent - 1;
            const int gsrc = (lane & 15) ^ (row & 7);
            gload_lds16(emb + (size_t)e * DIN + gsrc * 4, &s_emb[0][rb * 64]);
        }
        #pragma unroll
        for (int j = 0; j < 2; ++j) {
            const int gb = (wv * 2 + j) * 64;
            gload_lds16(weight + (size_t)(gb + lane) * 4, &s_w[0][gb * 4]);
        }
    }
    __builtin_amdgcn_sched_barrier(0);

    // ---- zero batch 0 (20 NT stores), queued behind the 6 loads
    vfloat4* outv = (vfloat4*)out;
    const vfloat4 z4 = {0.f, 0.f, 0.f, 0.f};
    const int zbase = blockIdx.x * (ZPT * 256) + tid;
    #pragma unroll
    for (int q = 0; q < 20; ++q) {
        int idx = zbase + q * 256;
        if (idx < zTotal4) __builtin_nontemporal_store(z4, &outv[idx]);
    }
    __builtin_amdgcn_sched_barrier(0);
    // in-order vmcnt retirement: outstanding<=20 => the 6 older loads are done
    asm volatile("s_waitcnt vmcnt(20)" ::: "memory");
    __builtin_amdgcn_sched_barrier(0);
    __builtin_amdgcn_s_barrier();

    float a0x=0.f,a0y=0.f,a0z=0.f,a0w=0.f;
    float a1x=0.f,a1y=0.f,a1z=0.f,a1w=0.f;

    for (int t = 0; t < 4; ++t) {
        const int cur = t & 1;

        // issue next-tile loads into buf^1 (before stores, before compute)
        if (t < 3) {
            const int nxt = cur ^ 1;
            const int kt  = (t + 1) * 64;
            const int r0  = wv * 16;
            #pragma unroll
            for (int j = 0; j < 4; ++j) {
                const int rb  = r0 + j * 4;
                const int row = rb + (lane >> 4);
                int e = eb + row; if (e >= nent) e = nent - 1;
                const int gsrc = (lane & 15) ^ (row & 7);
                gload_lds16(emb + (size_t)e * DIN + kt + gsrc * 4, &s_emb[nxt][rb * 64]);
            }
            #pragma unroll
            for (int j = 0; j < 2; ++j) {
                const int gb = (wv * 2 + j) * 64;
                gload_lds16(weight + (size_t)kt * DOUT + (size_t)(gb + lane) * 4,
                            &s_w[nxt][gb * 4]);
            }
        }
        __builtin_amdgcn_sched_barrier(0);

        // zero batch t+1 (20 NT stores, fire-and-forget)
        {
            const int qb = (t + 1) * 20;
            #pragma unroll
            for (int q = 0; q < 20; ++q) {
                int idx = zbase + (qb + q) * 256;
                if (idx < zTotal4) __builtin_nontemporal_store(z4, &outv[idx]);
            }
        }
        __builtin_amdgcn_sched_barrier(0);

        // compute tile t (LDS reads: 8-addr broadcasts, conflict-free via XOR)
        #pragma unroll
        for (int k4 = 0; k4 < 16; ++k4) {
            const int ec = ((k4 ^ es) << 2);
            const float4 e0 = *(const float4*)&s_emb[cur][eg * 64 + ec];
            const float4 e1 = *(const float4*)&s_emb[cur][(eg + 32) * 64 + ec];
            const float4 w0 = *(const float4*)&s_w[cur][(k4 * 4 + 0) * DOUT + og * 4];
            const float4 w1 = *(const float4*)&s_w[cur][(k4 * 4 + 1) * DOUT + og * 4];
            const float4 w2 = *(const float4*)&s_w[cur][(k4 * 4 + 2) * DOUT + og * 4];
            const float4 w3 = *(const float4*)&s_w[cur][(k4 * 4 + 3) * DOUT + og * 4];
            a0x += e0.x*w0.x + e0.y*w1.x + e0.z*w2.x + e0.w*w3.x;
            a0y += e0.x*w0.y + e0.y*w1.y + e0.z*w2.y + e0.w*w3.y;
            a0z += e0.x*w0.z + e0.y*w1.z + e0.z*w2.z + e0.w*w3.z;
            a0w += e0.x*w0.w + e0.y*w1.w + e0.z*w2.w + e0.w*w3.w;
            a1x += e1.x*w0.x + e1.y*w1.x + e1.z*w2.x + e1.w*w3.x;
            a1y += e1.x*w0.y + e1.y*w1.y + e1.z*w2.y + e1.w*w3.y;
            a1z += e1.x*w0.z + e1.y*w1.z + e1.z*w2.z + e1.w*w3.z;
            a1w += e1.x*w0.w + e1.y*w1.w + e1.z*w2.w + e1.w*w3.w;
        }

        if (t < 3) {
            // wait next-tile loads (<=20 newest stores may remain in flight)
            asm volatile("s_waitcnt vmcnt(20)" ::: "memory");
            __builtin_amdgcn_sched_barrier(0);
            __builtin_amdgcn_s_barrier();
        }
    }

    // ---- epilogue: bias + relu -> ws (stores drain at kernel end)
    const float4 bv = *(const float4*)&bias[og * 4];
    const int ent0 = eb + eg;
    if (ent0 < nent) {
        float4 r;
        r.x = fmaxf(a0x + bv.x, 0.f); r.y = fmaxf(a0y + bv.y, 0.f);
        r.z = fmaxf(a0z + bv.z, 0.f); r.w = fmaxf(a0w + bv.w, 0.f);
        *(float4*)&ws[(size_t)ent0 * DOUT + og * 4] = r;
    }
    const int ent1 = eb + eg + 32;
    if (ent1 < nent) {
        float4 r;
        r.x = fmaxf(a1x + bv.x, 0.f); r.y = fmaxf(a1y + bv.y, 0.f);
        r.z = fmaxf(a1z + bv.z, 0.f); r.w = fmaxf(a1w + bv.w, 0.f);
        *(float4*)&ws[(size_t)ent1 * DOUT + og * 4] = r;
    }
}

// k2: masked scatter-add of ws into the zeroed out (stream-ordered after k1)
__global__ __launch_bounds__(256)
void k2_scatter(const float* __restrict__ ws,
                const int* __restrict__ ex, const int* __restrict__ ey,
                const int* __restrict__ en, const int* __restrict__ pW,
                float* __restrict__ out, int N, int nent, int HW)
{
    const int idx = blockIdx.x * 256 + threadIdx.x;
    const int ent = idx >> 2;
    if (ent >= nent) return;
    const int b = ent / N, n = ent - b * N;
    if (n >= en[b]) return;
    const int cg = (idx & 3) * 8;
    const float4 v0 = *(const float4*)&ws[(size_t)ent * DOUT + cg];
    const float4 v1 = *(const float4*)&ws[(size_t)ent * DOUT + cg + 4];
    const int x = ex[ent], y = ey[ent];
    const int Wd = *pW;
    float* base = out + ((size_t)b * DOUT + cg) * (size_t)HW + (size_t)y * Wd + x;
    const float v[8] = {v0.x, v0.y, v0.z, v0.w, v1.x, v1.y, v1.z, v1.w};
    #pragma unroll
    for (int j = 0; j < 8; ++j)
        if (v[j] != 0.f) atomicAdd(base + (size_t)j * HW, v[j]);
}

// ---------------- fallback: memset + R4's proven fused kernel
constexpr int FET = 64, FKT = 64, FEP = FKT + 4;
__global__ __launch_bounds__(256)
void enc_fallback(const float* __restrict__ emb, const float* __restrict__ weight,
                  const float* __restrict__ bias, const int* __restrict__ ex,
                  const int* __restrict__ ey, const int* __restrict__ en,
                  const int* __restrict__ pW, float* __restrict__ out,
                  int N, int nent, int HW)
{
    __shared__ float s_emb[FET][FEP];
    __shared__ float s_w[FKT * DOUT];
    const int tid = threadIdx.x;
    const int og = tid & 7, eg = tid >> 3;
    const int eb = blockIdx.x * FET;
    float4 pe[4]; float4 pw[2];
    #pragma unroll
    for (int r = 0; r < 4; ++r) {
        int f = (r << 8) + tid, row = f >> 4, col = (f & 15) << 2;
        int e = eb + row; if (e >= nent) e = nent - 1;
        pe[r] = *(const float4*)&emb[(size_t)e * DIN + col];
    }
    #pragma unroll
    for (int r = 0; r < 2; ++r) pw[r] = *(const float4*)&weight[(size_t)(((r << 8) + tid) << 2)];
    float acc[2][4] = {{0,0,0,0},{0,0,0,0}};
    for (int t = 0; t < 4; ++t) {
        #pragma unroll
        for (int r = 0; r < 4; ++r) {
            int f = (r << 8) + tid;
            *(float4*)&s_emb[f >> 4][(f & 15) << 2] = pe[r];
        }
        #pragma unroll
        for (int r = 0; r < 2; ++r) *(float4*)&s_w[((r << 8) + tid) << 2] = pw[r];
        __syncthreads();
        if (t < 3) {
            const int kt = (t + 1) * FKT;
            #pragma unroll
            for (int r = 0; r < 4; ++r) {
                int f = (r << 8) + tid, row = f >> 4, col = (f & 15) << 2;
                int e = eb + row; if (e >= nent) e = nent - 1;
                pe[r] = *(const float4*)&emb[(size_t)e * DIN + kt + col];
            }
            #pragma unroll
            for (int r = 0; r < 2; ++r)
                pw[r] = *(const float4*)&weight[(size_t)kt * DOUT + (((r << 8) + tid) << 2)];
        }
        #pragma unroll
        for (int k = 0; k < FKT; k += 4) {
            float4 e0 = *(const float4*)&s_emb[eg][k];
            float4 e1 = *(const float4*)&s_emb[eg + 32][k];
            float4 w0 = *(const float4*)&s_w[(k + 0) * DOUT + og * 4];
            float4 w1 = *(const float4*)&s_w[(k + 1) * DOUT + og * 4];
            float4 w2 = *(const float4*)&s_w[(k + 2) * DOUT + og * 4];
            float4 w3 = *(const float4*)&s_w[(k + 3) * DOUT + og * 4];
            acc[0][0] += e0.x*w0.x + e0.y*w1.x + e0.z*w2.x + e0.w*w3.x;
            acc[0][1] += e0.x*w0.y + e0.y*w1.y + e0.z*w2.y + e0.w*w3.y;
            acc[0][2] += e0.x*w0.z + e0.y*w1.z + e0.z*w2.z + e0.w*w3.z;
            acc[0][3] += e0.x*w0.w + e0.y*w1.w + e0.z*w2.w + e0.w*w3.w;
            acc[1][0] += e1.x*w0.x + e1.y*w1.x + e1.z*w2.x + e1.w*w3.x;
            acc[1][1] += e1.x*w0.y + e1.y*w1.y + e1.z*w2.y + e1.w*w3.y;
            acc[1][2] += e1.x*w0.z + e1.y*w1.z + e1.z*w2.z + e1.w*w3.z;
            acc[1][3] += e1.x*w0.w + e1.y*w1.w + e1.z*w2.w + e1.w*w3.w;
        }
        __syncthreads();
    }
    const int W = *pW;
    const float4 bv = *(const float4*)&bias[og * 4];
    #pragma unroll
    for (int i = 0; i < 2; ++i) {
        int ent = eb + eg + i * 32;
        if (ent >= nent) continue;
        int b = ent / N, n = ent - b * N;
        if (n >= en[b]) continue;
        float* dst = out + ((size_t)b * DOUT + og * 4) * (size_t)HW
                         + (size_t)ey[ent] * W + ex[ent];
        float v0 = fmaxf(acc[i][0] + bv.x, 0.f);
        float v1 = fmaxf(acc[i][1] + bv.y, 0.f);
        float v2 = fmaxf(acc[i][2] + bv.z, 0.f);
        float v3 = fmaxf(acc[i][3] + bv.w, 0.f);
        if (v0 != 0.f) atomicAdd(dst + 0 * (size_t)HW, v0);
        if (v1 != 0.f) atomicAdd(dst + 1 * (size_t)HW, v1);
        if (v2 != 0.f) atomicAdd(dst + 2 * (size_t)HW, v2);
        if (v3 != 0.f) atomicAdd(dst + 3 * (size_t)HW, v3);
    }
}

extern "C" void kernel_launch(void* const* d_in, const int* in_sizes, int n_in,
                              void* d_out, int out_size, void* d_ws, size_t ws_size,
                              hipStream_t stream) {
    const float* emb    = (const float*)d_in[0];
    const float* weight = (const float*)d_in[1];
    const float* bias   = (const float*)d_in[2];
    const int*   ex     = (const int*)d_in[3];
    const int*   ey     = (const int*)d_in[4];
    const int*   en     = (const int*)d_in[5];
    const int*   pW     = (const int*)d_in[7];
    float*       out    = (float*)d_out;

    const int nent = in_sizes[3];          // B*N
    const int B    = in_sizes[5];
    const int N    = nent / B;
    const int HW   = (int)((size_t)out_size / ((size_t)B * DOUT));
    const int zTotal4 = out_size / 4;

    const int blocks1 = (nent + ET - 1) / ET;
    const bool fits = (ws_size >= (size_t)nent * DOUT * sizeof(float)) &&
                      (out_size % 4 == 0) &&
                      ((size_t)blocks1 * ZPT * 256 >= (size_t)zTotal4);

    if (fits) {
        k1_zero_gemm<<<blocks1, 256, 0, stream>>>(emb, weight, bias, out,
                                                  (float*)d_ws, nent, zTotal4);
        const int blocks2 = (nent * 4 + 255) / 256;
        k2_scatter<<<blocks2, 256, 0, stream>>>((const float*)d_ws, ex, ey, en, pW,
                                                out, N, nent, HW);
    } else {
        (void)hipMemsetAsync(d_out, 0, (size_t)out_size * sizeof(float), stream);
        const int blocks = (nent + FET - 1) / FET;
        enc_fallback<<<blocks, 256, 0, stream>>>(emb, weight, bias, ex, ey, en, pW,
                                                 out, N, nent, HW);
    }
}